// Round 1
// baseline (266.667 us; speedup 1.0000x reference)
//
#include <hip/hip_runtime.h>

// GNN collapse: out = A^8 (x · w_in) + sum_l gamma_l A^{8-l} 1 + b_dec
// where A = D_in^-1/2 Adj D_out^-1/2 (scalar field propagation).

__global__ void count_kernel(const int* __restrict__ src, const int* __restrict__ dst,
                             int* __restrict__ cnt_out, int* __restrict__ cnt_in, int E) {
    for (int i = blockIdx.x * blockDim.x + threadIdx.x; i < E; i += gridDim.x * blockDim.x) {
        atomicAdd(&cnt_out[src[i]], 1);
        atomicAdd(&cnt_in[dst[i]], 1);
    }
}

__global__ void inv_kernel(const int* __restrict__ cnt_out, const int* __restrict__ cnt_in,
                           float* __restrict__ inv_out, float* __restrict__ inv_in, int N) {
    int n = blockIdx.x * blockDim.x + threadIdx.x;
    if (n < N) {
        int co = cnt_out[n]; if (co < 1) co = 1;
        int ci = cnt_in[n];  if (ci < 1) ci = 1;
        inv_out[n] = rsqrtf((float)co);
        inv_in[n]  = rsqrtf((float)ci);
    }
}

// Single-block chunked exclusive scan of cnt_in -> row_start[0..N]
__global__ __launch_bounds__(1024) void scan_kernel(const int* __restrict__ cnt,
                                                    int* __restrict__ row_start, int N) {
    __shared__ int wsum[16];
    int tid = threadIdx.x;
    int chunk = (N + 1023) / 1024;
    int lo = tid * chunk;
    int hi = lo + chunk; if (hi > N) hi = N;
    int s = 0;
    for (int i = lo; i < hi; ++i) s += cnt[i];
    int lane = tid & 63, wv = tid >> 6;
    int x = s;
    for (int d = 1; d < 64; d <<= 1) { int t = __shfl_up(x, d); if (lane >= d) x += t; }
    if (lane == 63) wsum[wv] = x;
    __syncthreads();
    if (wv == 0) {
        int y = (lane < 16) ? wsum[lane] : 0;
        for (int d = 1; d < 16; d <<= 1) { int t = __shfl_up(y, d); if (lane >= d) y += t; }
        if (lane < 16) wsum[lane] = y;
    }
    __syncthreads();
    int base = (wv ? wsum[wv - 1] : 0) + (x - s);  // exclusive prefix of this thread's chunk
    int run = base;
    for (int i = lo; i < hi; ++i) { row_start[i] = run; run += cnt[i]; }
    if (hi == N && lo <= N) row_start[N] = run;   // threads past the end also write the total
}

__global__ void fill_kernel(const int* __restrict__ src, const int* __restrict__ dst,
                            const int* __restrict__ row_start, int* __restrict__ cursor,
                            int* __restrict__ csr, int E) {
    for (int i = blockIdx.x * blockDim.x + threadIdx.x; i < E; i += gridDim.x * blockDim.x) {
        int d = dst[i];
        int pos = row_start[d] + atomicAdd(&cursor[d], 1);
        csr[pos] = src[i];
    }
}

// One wave: V chain v = W_l..W_8 W_dec; gammas; w_in = W_embed @ V_1.
// coef[0..8] = gamma_0..gamma_8, coef[16..47] = w_in[0..31]
__global__ void coeff_kernel(const float* __restrict__ W_embed, const float* __restrict__ b_embed,
                             const float* __restrict__ Ws, const float* __restrict__ bs,
                             const float* __restrict__ W_dec, float* __restrict__ coef) {
    __shared__ float v[64];
    __shared__ float g[9];
    int i = threadIdx.x;  // 64 threads
    v[i] = W_dec[i];
    __syncthreads();
    for (int l = 7; l >= 0; --l) {   // layer number l+1, current v = V_{l+2}
        float p = bs[l * 64 + i] * v[i];
        for (int d = 32; d; d >>= 1) p += __shfl_xor(p, d);
        if (i == 0) g[l + 1] = p;
        float a = 0.f;
        const float* Wrow = Ws + l * 4096 + i * 64;
        for (int j = 0; j < 64; ++j) a += Wrow[j] * v[j];
        __syncthreads();
        v[i] = a;                     // v = V_{l+1}
        __syncthreads();
    }
    float p = b_embed[i] * v[i];      // gamma_0 = b_embed . V_1
    for (int d = 32; d; d >>= 1) p += __shfl_xor(p, d);
    if (i == 0) g[0] = p;
    __syncthreads();
    if (i < 32) {
        float a = 0.f;
        const float* Wr = W_embed + i * 64;
        for (int j = 0; j < 64; ++j) a += Wr[j] * v[j];
        coef[16 + i] = a;
    }
    if (i < 9) coef[i] = g[i];
}

// ts0[n] = inv_out[n] * (x[n,:] . w_in + gamma_0)
__global__ __launch_bounds__(256) void z0_kernel(const float* __restrict__ x,
                                                 const float* __restrict__ coef,
                                                 const float* __restrict__ inv_out,
                                                 float* __restrict__ ts0, int N) {
    __shared__ float w[32];
    __shared__ float g0;
    if (threadIdx.x < 32) w[threadIdx.x] = coef[16 + threadIdx.x];
    if (threadIdx.x == 0) g0 = coef[0];
    __syncthreads();
    int n = blockIdx.x * blockDim.x + threadIdx.x;
    if (n >= N) return;
    const float4* xr = (const float4*)(x + (size_t)n * 32);
    float acc = 0.f;
#pragma unroll
    for (int q = 0; q < 8; ++q) {
        float4 vv = xr[q];
        acc += vv.x * w[q * 4] + vv.y * w[q * 4 + 1] + vv.z * w[q * 4 + 2] + vv.w * w[q * 4 + 3];
    }
    ts0[n] = inv_out[n] * (acc + g0);
}

// ts_out[n] = inv_out[n] * (inv_in[n] * sum_{e in in(n)} ts_in[csr[e]] + gamma_k)
__global__ __launch_bounds__(256) void prop_kernel(const float* __restrict__ ts_in,
                                                   float* __restrict__ ts_out,
                                                   const float* __restrict__ inv_out,
                                                   const float* __restrict__ inv_in,
                                                   const int* __restrict__ row_start,
                                                   const int* __restrict__ csr,
                                                   const float* __restrict__ coef, int k, int N) {
    int n = blockIdx.x * blockDim.x + threadIdx.x;
    if (n >= N) return;
    int e0 = row_start[n], e1 = row_start[n + 1];
    float acc = 0.f;
    int e = e0;
    for (; e + 3 < e1; e += 4) {
        int s0 = csr[e], s1 = csr[e + 1], s2 = csr[e + 2], s3 = csr[e + 3];
        acc += ts_in[s0] + ts_in[s1] + ts_in[s2] + ts_in[s3];
    }
    for (; e < e1; ++e) acc += ts_in[csr[e]];
    float t = inv_in[n] * acc + coef[k];
    ts_out[n] = inv_out[n] * t;
}

// out[n] = inv_in[n] * sum ts_in[csr[e]] + gamma_8 + b_dec
__global__ __launch_bounds__(256) void final_kernel(const float* __restrict__ ts_in,
                                                    float* __restrict__ out,
                                                    const float* __restrict__ inv_in,
                                                    const int* __restrict__ row_start,
                                                    const int* __restrict__ csr,
                                                    const float* __restrict__ coef,
                                                    const float* __restrict__ b_dec, int N) {
    int n = blockIdx.x * blockDim.x + threadIdx.x;
    if (n >= N) return;
    int e0 = row_start[n], e1 = row_start[n + 1];
    float acc = 0.f;
    int e = e0;
    for (; e + 3 < e1; e += 4) {
        int s0 = csr[e], s1 = csr[e + 1], s2 = csr[e + 2], s3 = csr[e + 3];
        acc += ts_in[s0] + ts_in[s1] + ts_in[s2] + ts_in[s3];
    }
    for (; e < e1; ++e) acc += ts_in[csr[e]];
    out[n] = inv_in[n] * acc + coef[8] + b_dec[0];
}

extern "C" void kernel_launch(void* const* d_in, const int* in_sizes, int n_in,
                              void* d_out, int out_size, void* d_ws, size_t ws_size,
                              hipStream_t stream) {
    const float* x       = (const float*)d_in[0];
    const int*   src     = (const int*)d_in[1];
    const int*   dst     = (const int*)d_in[2];
    const float* W_embed = (const float*)d_in[3];
    const float* b_embed = (const float*)d_in[4];
    const float* Ws      = (const float*)d_in[5];
    const float* bs      = (const float*)d_in[6];
    const float* W_dec   = (const float*)d_in[7];
    const float* b_dec   = (const float*)d_in[8];
    float* out = (float*)d_out;
    int N = in_sizes[0] / 32;
    int E = in_sizes[1];

    char* w = (char*)d_ws;
    size_t o = 0;
    int* cnt_out = (int*)(w + o); o += (size_t)N * 4;
    int* cnt_in  = (int*)(w + o); o += (size_t)N * 4;
    int* cursor  = (int*)(w + o); o += (size_t)N * 4;
    o = (o + 255) & ~(size_t)255;
    int* row_start = (int*)(w + o); o += (size_t)(N + 1) * 4; o = (o + 255) & ~(size_t)255;
    float* inv_out = (float*)(w + o); o += (size_t)N * 4; o = (o + 255) & ~(size_t)255;
    float* inv_in  = (float*)(w + o); o += (size_t)N * 4; o = (o + 255) & ~(size_t)255;
    int* csr       = (int*)(w + o); o += (size_t)E * 4; o = (o + 255) & ~(size_t)255;
    float* coef    = (float*)(w + o); o += 256;
    float* tsA     = (float*)(w + o); o += (size_t)N * 4; o = (o + 255) & ~(size_t)255;
    float* tsB     = (float*)(w + o);

    hipMemsetAsync(cnt_out, 0, (size_t)N * 3 * 4, stream);  // cnt_out, cnt_in, cursor

    coeff_kernel<<<1, 64, 0, stream>>>(W_embed, b_embed, Ws, bs, W_dec, coef);

    int ebl = (E + 255) / 256;
    int nbl = (N + 255) / 256;
    count_kernel<<<ebl, 256, 0, stream>>>(src, dst, cnt_out, cnt_in, E);
    inv_kernel<<<nbl, 256, 0, stream>>>(cnt_out, cnt_in, inv_out, inv_in, N);
    scan_kernel<<<1, 1024, 0, stream>>>(cnt_in, row_start, N);
    fill_kernel<<<ebl, 256, 0, stream>>>(src, dst, row_start, cursor, csr, E);

    z0_kernel<<<nbl, 256, 0, stream>>>(x, coef, inv_out, tsA, N);

    float* ta = tsA; float* tb = tsB;
    for (int k = 1; k <= 7; ++k) {
        prop_kernel<<<nbl, 256, 0, stream>>>(ta, tb, inv_out, inv_in, row_start, csr, coef, k, N);
        float* tmp = ta; ta = tb; tb = tmp;
    }
    final_kernel<<<nbl, 256, 0, stream>>>(ta, out, inv_in, row_start, csr, coef, b_dec, N);
}

// Round 2
// 201.453 us; speedup vs baseline: 1.3237x; 1.3237x over previous
//
#include <hip/hip_runtime.h>

// GNN collapse: out = A^8 (x · w_in) + sum_l gamma_l A^{8-l} 1 + b_dec
// where A = D_in^-1/2 Adj D_out^-1/2 (scalar field propagation).

#define SCAN_CHUNK 1024   // elements per block in hierarchical scan

__global__ void count_kernel(const int* __restrict__ src, const int* __restrict__ dst,
                             int* __restrict__ cnt_out, int* __restrict__ cnt_in, int E) {
    for (int i = blockIdx.x * blockDim.x + threadIdx.x; i < E; i += gridDim.x * blockDim.x) {
        atomicAdd(&cnt_out[src[i]], 1);
        atomicAdd(&cnt_in[dst[i]], 1);
    }
}

__global__ void inv_kernel(const int* __restrict__ cnt_out, const int* __restrict__ cnt_in,
                           float* __restrict__ inv_out, float* __restrict__ inv_in, int N) {
    int n = blockIdx.x * blockDim.x + threadIdx.x;
    if (n < N) {
        int co = cnt_out[n]; if (co < 1) co = 1;
        int ci = cnt_in[n];  if (ci < 1) ci = 1;
        inv_out[n] = rsqrtf((float)co);
        inv_in[n]  = rsqrtf((float)ci);
    }
}

// ---- hierarchical scan: pass 1 — per-block sums of SCAN_CHUNK elements ----
__global__ __launch_bounds__(256) void scan_sum_kernel(const int* __restrict__ cnt,
                                                       int* __restrict__ blk_sum, int N) {
    __shared__ int wsum[4];
    int base = blockIdx.x * SCAN_CHUNK + threadIdx.x * 4;
    int s = 0;
#pragma unroll
    for (int j = 0; j < 4; ++j) { int i = base + j; if (i < N) s += cnt[i]; }
    int x = s;
    for (int d = 1; d < 64; d <<= 1) { int t = __shfl_up(x, d); if ((threadIdx.x & 63) >= d) x += t; }
    if ((threadIdx.x & 63) == 63) wsum[threadIdx.x >> 6] = x;
    __syncthreads();
    if (threadIdx.x == 0) blk_sum[blockIdx.x] = wsum[0] + wsum[1] + wsum[2] + wsum[3];
}

// ---- pass 2 — single-wave exclusive scan of block sums (B <= 64) ----
__global__ void scan_blk_kernel(int* __restrict__ blk_sum, int* __restrict__ blk_off,
                                int* __restrict__ row_start, int B, int N) {
    int i = threadIdx.x;  // 64 threads
    int v = (i < B) ? blk_sum[i] : 0;
    int x = v;
    for (int d = 1; d < 64; d <<= 1) { int t = __shfl_up(x, d); if (i >= d) x += t; }
    if (i < B) blk_off[i] = x - v;           // exclusive
    if (i == 63) row_start[N] = x;           // total
}

// ---- pass 3 — re-read chunk, in-block exclusive scan + block offset ----
__global__ __launch_bounds__(256) void scan_write_kernel(const int* __restrict__ cnt,
                                                         const int* __restrict__ blk_off,
                                                         int* __restrict__ row_start, int N) {
    __shared__ int wsum[4];
    int base = blockIdx.x * SCAN_CHUNK + threadIdx.x * 4;
    int c[4]; int s = 0;
#pragma unroll
    for (int j = 0; j < 4; ++j) { int i = base + j; c[j] = (i < N) ? cnt[i] : 0; s += c[j]; }
    int lane = threadIdx.x & 63, wv = threadIdx.x >> 6;
    int x = s;
    for (int d = 1; d < 64; d <<= 1) { int t = __shfl_up(x, d); if (lane >= d) x += t; }
    if (lane == 63) wsum[wv] = x;
    __syncthreads();
    int wbase = 0;
    for (int j = 0; j < 4; ++j) { if (j < wv) wbase += wsum[j]; }
    int run = blk_off[blockIdx.x] + wbase + (x - s);   // exclusive prefix of this thread
#pragma unroll
    for (int j = 0; j < 4; ++j) {
        int i = base + j;
        if (i < N) row_start[i] = run;
        run += c[j];
    }
}

__global__ void fill_kernel(const int* __restrict__ src, const int* __restrict__ dst,
                            const int* __restrict__ row_start, int* __restrict__ cursor,
                            int* __restrict__ csr, int E) {
    for (int i = blockIdx.x * blockDim.x + threadIdx.x; i < E; i += gridDim.x * blockDim.x) {
        int d = dst[i];
        int pos = row_start[d] + atomicAdd(&cursor[d], 1);
        csr[pos] = src[i];
    }
}

// One wave: V chain v = W_l..W_8 W_dec; gammas; w_in = W_embed @ V_1.
// coef[0..8] = gamma_0..gamma_8, coef[16..47] = w_in[0..31]
__global__ void coeff_kernel(const float* __restrict__ W_embed, const float* __restrict__ b_embed,
                             const float* __restrict__ Ws, const float* __restrict__ bs,
                             const float* __restrict__ W_dec, float* __restrict__ coef) {
    __shared__ float v[64];
    __shared__ float g[9];
    int i = threadIdx.x;  // 64 threads
    v[i] = W_dec[i];
    __syncthreads();
    for (int l = 7; l >= 0; --l) {
        float p = bs[l * 64 + i] * v[i];
        for (int d = 32; d; d >>= 1) p += __shfl_xor(p, d);
        if (i == 0) g[l + 1] = p;
        float a = 0.f;
        const float* Wrow = Ws + l * 4096 + i * 64;
        for (int j = 0; j < 64; ++j) a += Wrow[j] * v[j];
        __syncthreads();
        v[i] = a;
        __syncthreads();
    }
    float p = b_embed[i] * v[i];
    for (int d = 32; d; d >>= 1) p += __shfl_xor(p, d);
    if (i == 0) g[0] = p;
    __syncthreads();
    if (i < 32) {
        float a = 0.f;
        const float* Wr = W_embed + i * 64;
        for (int j = 0; j < 64; ++j) a += Wr[j] * v[j];
        coef[16 + i] = a;
    }
    if (i < 9) coef[i] = g[i];
}

// ts0[n] = inv_out[n] * (x[n,:] . w_in + gamma_0)
__global__ __launch_bounds__(256) void z0_kernel(const float* __restrict__ x,
                                                 const float* __restrict__ coef,
                                                 const float* __restrict__ inv_out,
                                                 float* __restrict__ ts0, int N) {
    __shared__ float w[32];
    __shared__ float g0;
    if (threadIdx.x < 32) w[threadIdx.x] = coef[16 + threadIdx.x];
    if (threadIdx.x == 0) g0 = coef[0];
    __syncthreads();
    int n = blockIdx.x * blockDim.x + threadIdx.x;
    if (n >= N) return;
    const float4* xr = (const float4*)(x + (size_t)n * 32);
    float acc = 0.f;
#pragma unroll
    for (int q = 0; q < 8; ++q) {
        float4 vv = xr[q];
        acc += vv.x * w[q * 4] + vv.y * w[q * 4 + 1] + vv.z * w[q * 4 + 2] + vv.w * w[q * 4 + 3];
    }
    ts0[n] = inv_out[n] * (acc + g0);
}

// ts_out[n] = inv_out[n] * (inv_in[n] * sum_{e in in(n)} ts_in[csr[e]] + gamma_k)
__global__ __launch_bounds__(256) void prop_kernel(const float* __restrict__ ts_in,
                                                   float* __restrict__ ts_out,
                                                   const float* __restrict__ inv_out,
                                                   const float* __restrict__ inv_in,
                                                   const int* __restrict__ row_start,
                                                   const int* __restrict__ csr,
                                                   const float* __restrict__ coef, int k, int N) {
    int n = blockIdx.x * blockDim.x + threadIdx.x;
    if (n >= N) return;
    int e0 = row_start[n], e1 = row_start[n + 1];
    float acc = 0.f;
    int e = e0;
    for (; e + 3 < e1; e += 4) {
        int s0 = csr[e], s1 = csr[e + 1], s2 = csr[e + 2], s3 = csr[e + 3];
        acc += ts_in[s0] + ts_in[s1] + ts_in[s2] + ts_in[s3];
    }
    for (; e < e1; ++e) acc += ts_in[csr[e]];
    float t = inv_in[n] * acc + coef[k];
    ts_out[n] = inv_out[n] * t;
}

// out[n] = inv_in[n] * sum ts_in[csr[e]] + gamma_8 + b_dec
__global__ __launch_bounds__(256) void final_kernel(const float* __restrict__ ts_in,
                                                    float* __restrict__ out,
                                                    const float* __restrict__ inv_in,
                                                    const int* __restrict__ row_start,
                                                    const int* __restrict__ csr,
                                                    const float* __restrict__ coef,
                                                    const float* __restrict__ b_dec, int N) {
    int n = blockIdx.x * blockDim.x + threadIdx.x;
    if (n >= N) return;
    int e0 = row_start[n], e1 = row_start[n + 1];
    float acc = 0.f;
    int e = e0;
    for (; e + 3 < e1; e += 4) {
        int s0 = csr[e], s1 = csr[e + 1], s2 = csr[e + 2], s3 = csr[e + 3];
        acc += ts_in[s0] + ts_in[s1] + ts_in[s2] + ts_in[s3];
    }
    for (; e < e1; ++e) acc += ts_in[csr[e]];
    out[n] = inv_in[n] * acc + coef[8] + b_dec[0];
}

extern "C" void kernel_launch(void* const* d_in, const int* in_sizes, int n_in,
                              void* d_out, int out_size, void* d_ws, size_t ws_size,
                              hipStream_t stream) {
    const float* x       = (const float*)d_in[0];
    const int*   src     = (const int*)d_in[1];
    const int*   dst     = (const int*)d_in[2];
    const float* W_embed = (const float*)d_in[3];
    const float* b_embed = (const float*)d_in[4];
    const float* Ws      = (const float*)d_in[5];
    const float* bs      = (const float*)d_in[6];
    const float* W_dec   = (const float*)d_in[7];
    const float* b_dec   = (const float*)d_in[8];
    float* out = (float*)d_out;
    int N = in_sizes[0] / 32;
    int E = in_sizes[1];

    char* w = (char*)d_ws;
    size_t o = 0;
    int* cnt_out = (int*)(w + o); o += (size_t)N * 4;
    int* cnt_in  = (int*)(w + o); o += (size_t)N * 4;
    int* cursor  = (int*)(w + o); o += (size_t)N * 4;
    o = (o + 255) & ~(size_t)255;
    int* row_start = (int*)(w + o); o += (size_t)(N + 1) * 4; o = (o + 255) & ~(size_t)255;
    float* inv_out = (float*)(w + o); o += (size_t)N * 4; o = (o + 255) & ~(size_t)255;
    float* inv_in  = (float*)(w + o); o += (size_t)N * 4; o = (o + 255) & ~(size_t)255;
    int* csr       = (int*)(w + o); o += (size_t)E * 4; o = (o + 255) & ~(size_t)255;
    float* coef    = (float*)(w + o); o += 256;
    float* tsA     = (float*)(w + o); o += (size_t)N * 4; o = (o + 255) & ~(size_t)255;
    float* tsB     = (float*)(w + o); o += (size_t)N * 4; o = (o + 255) & ~(size_t)255;
    int* blk_sum   = (int*)(w + o); o += 4096;
    int* blk_off   = (int*)(w + o); o += 4096;

    hipMemsetAsync(cnt_out, 0, (size_t)N * 3 * 4, stream);  // cnt_out, cnt_in, cursor

    coeff_kernel<<<1, 64, 0, stream>>>(W_embed, b_embed, Ws, bs, W_dec, coef);

    int ebl = (E + 255) / 256;
    int nbl = (N + 255) / 256;
    int B = (N + SCAN_CHUNK - 1) / SCAN_CHUNK;  // <= 64 for N <= 65536
    count_kernel<<<ebl, 256, 0, stream>>>(src, dst, cnt_out, cnt_in, E);
    inv_kernel<<<nbl, 256, 0, stream>>>(cnt_out, cnt_in, inv_out, inv_in, N);
    scan_sum_kernel<<<B, 256, 0, stream>>>(cnt_in, blk_sum, N);
    scan_blk_kernel<<<1, 64, 0, stream>>>(blk_sum, blk_off, row_start, B, N);
    scan_write_kernel<<<B, 256, 0, stream>>>(cnt_in, blk_off, row_start, N);
    fill_kernel<<<ebl, 256, 0, stream>>>(src, dst, row_start, cursor, csr, E);

    z0_kernel<<<nbl, 256, 0, stream>>>(x, coef, inv_out, tsA, N);

    float* ta = tsA; float* tb = tsB;
    for (int k = 1; k <= 7; ++k) {
        prop_kernel<<<nbl, 256, 0, stream>>>(ta, tb, inv_out, inv_in, row_start, csr, coef, k, N);
        float* tmp = ta; ta = tb; tb = tmp;
    }
    final_kernel<<<nbl, 256, 0, stream>>>(ta, out, inv_in, row_start, csr, coef, b_dec, N);
}